// Round 1
// baseline (66.625 us; speedup 1.0000x reference)
//
#include <hip/hip_runtime.h>

// ROI max-pool (aspect-preserving "OCR" variant).
// feats: (B=4, C=128, H=64, W=512) fp32
// rois:  (N, 5) fp32 = [batch, x1, y1, x2, y2] in image coords (spatial scale 0.25)
// out:   (N, C, PH=8, PW=32) fp32

#define PHB 8
#define PWB 32

__global__ __launch_bounds__(256) void ocr_roi_pool_kernel(
    const float* __restrict__ feats,
    const float* __restrict__ rois,
    float* __restrict__ out,
    int total, int Cc, int Hc, int Wc)
{
#pragma clang fp contract(off)
    int t = blockIdx.x * 256 + threadIdx.x;
    if (t >= total) return;

    // bit layout matches output (n, c, ph, pw) with C=128, PH=8, PW=32
    int pw = t & 31;
    int ph = (t >> 5) & 7;
    int c  = (t >> 8) & 127;
    int n  = t >> 15;

    const float* r = rois + n * 5;
    int   rb = (int)r[0];
    // _round(x) = floor(x + 0.5), scale = 0.25 exactly as reference (no FMA contraction)
    float sx1 = r[1] * 0.25f;
    float sy1 = r[2] * 0.25f;
    float sx2 = r[3] * 0.25f;
    float sy2 = r[4] * 0.25f;
    int rsw = (int)floorf(sx1 + 0.5f);
    int rsh = (int)floorf(sy1 + 0.5f);
    int rew = (int)floorf(sx2 + 0.5f);
    int reh = (int)floorf(sy2 + 0.5f);

    int roi_w = max(rew - rsw + 1, 1);
    int roi_h = max(reh - rsh + 1, 1);
    int rpw   = (PHB * roi_w + roi_h - 1) / roi_h;   // pooled width (aspect-preserving)

    float bsh = (float)roi_h / (float)PHB;
    float bsw = (float)roi_w / (float)rpw;

    int hs = (int)floorf((float)ph * bsh) + rsh;
    int he = (int)ceilf((float)(ph + 1) * bsh) + rsh;
    int ws = (int)floorf((float)pw * bsw) + rsw;
    int we = (int)ceilf((float)(pw + 1) * bsw) + rsw;

    hs = min(max(hs, 0), Hc);
    he = min(max(he, 0), Hc);
    ws = min(max(ws, 0), Wc);
    we = min(max(we, 0), Wc);

    bool pad   = (ws >= rew);
    bool empty = (he <= hs) || (we <= ws);

    float m = 0.0f;
    if (!(pad || empty)) {
        m = -1e37f;
        const float* base = feats + ((size_t)(rb * Cc + c) * Hc) * Wc;
        for (int h = hs; h < he; ++h) {
            const float* row = base + (size_t)h * Wc;
            for (int w = ws; w < we; ++w) {
                m = fmaxf(m, row[w]);
            }
        }
    }
    out[t] = m;
}

extern "C" void kernel_launch(void* const* d_in, const int* in_sizes, int n_in,
                              void* d_out, int out_size, void* d_ws, size_t ws_size,
                              hipStream_t stream) {
    const float* feats = (const float*)d_in[0];
    const float* rois  = (const float*)d_in[1];
    float* out = (float*)d_out;

    const int Cc = 128, Hc = 64, Wc = 512;
    int nroi = in_sizes[1] / 5;
    int total = nroi * Cc * PHB * PWB;   // == out_size
    int blocks = (total + 255) / 256;

    ocr_roi_pool_kernel<<<blocks, 256, 0, stream>>>(feats, rois, out, total, Cc, Hc, Wc);
}

// Round 2
// 48.303 us; speedup vs baseline: 1.3793x; 1.3793x over previous
//
#include <hip/hip_runtime.h>

// ROI max-pool (aspect-preserving "OCR" variant).
// feats: (B=4, C=128, H=64, W=512) fp32
// rois:  (N, 5) fp32 = [batch, x1, y1, x2, y2] image coords, spatial scale 0.25
// out:   (N, C, PH=8, PW=32) fp32
//
// Block = one (roi, channel-group-of-8): 256 threads = the 8x32 output bins.
// n / channel group derived from blockIdx only -> ROI params and the 8 feature
// base pointers are wave-uniform (SGPR), so the inner loop is 1 voffset calc +
// 8 scalar-base loads + 8 v_max per bin pixel.

#define PHB 8
#define PWB 32
#define CPT 8   // channels per thread

__global__ __launch_bounds__(256) void ocr_roi_pool_kernel(
    const float* __restrict__ feats,
    const float* __restrict__ rois,
    float* __restrict__ out,
    int Cc, int Hc, int Wc)
{
#pragma clang fp contract(off)
    const int ngroups = 128 / CPT;                 // 16
    int n  = blockIdx.x / ngroups;                 // roi index  (uniform)
    int cg = blockIdx.x - n * ngroups;             // channel grp (uniform)
    int c0 = cg * CPT;

    int t  = threadIdx.x;
    int pw = t & 31;
    int ph = t >> 5;

    // ---- ROI params: block-uniform -> scalar ----
    const float* r = rois + n * 5;
    int   rb  = (int)r[0];
    int rsw = (int)floorf(r[1] * 0.25f + 0.5f);
    int rsh = (int)floorf(r[2] * 0.25f + 0.5f);
    int rew = (int)floorf(r[3] * 0.25f + 0.5f);
    int reh = (int)floorf(r[4] * 0.25f + 0.5f);

    int roi_w = max(rew - rsw + 1, 1);
    int roi_h = max(reh - rsh + 1, 1);
    int rpw   = (PHB * roi_w + roi_h - 1) / roi_h;

    float bsh = (float)roi_h / (float)PHB;
    float bsw = (float)roi_w / (float)rpw;

    // ---- per-thread bin bounds (exact reference math) ----
    int hs = (int)floorf((float)ph * bsh) + rsh;
    int he = (int)ceilf((float)(ph + 1) * bsh) + rsh;
    int ws = (int)floorf((float)pw * bsw) + rsw;
    int we = (int)ceilf((float)(pw + 1) * bsw) + rsw;

    hs = min(max(hs, 0), Hc);
    he = min(max(he, 0), Hc);
    ws = min(max(ws, 0), Wc);
    we = min(max(we, 0), Wc);

    bool pad   = (ws >= rew);
    bool empty = (he <= hs) || (we <= ws);

    // ---- 8 uniform channel-plane base pointers (SGPR) ----
    const float* base[CPT];
#pragma unroll
    for (int k = 0; k < CPT; ++k)
        base[k] = feats + ((size_t)(rb * Cc + c0 + k) * Hc) * Wc;

    float m[CPT];
#pragma unroll
    for (int k = 0; k < CPT; ++k) m[k] = -1e37f;

    if (!(pad || empty)) {
        for (int h = hs; h < he; ++h) {
            int rowoff = h * Wc;
            for (int w = ws; w < we; ++w) {
                int off = rowoff + w;
#pragma unroll
                for (int k = 0; k < CPT; ++k)
                    m[k] = fmaxf(m[k], base[k][off]);
            }
        }
    } else {
#pragma unroll
        for (int k = 0; k < CPT; ++k) m[k] = 0.0f;
    }

    // ---- store: (n, c, ph, pw) ----
    size_t obase = ((size_t)n * Cc + c0) * (PHB * PWB) + ph * PWB + pw;
#pragma unroll
    for (int k = 0; k < CPT; ++k)
        out[obase + (size_t)k * (PHB * PWB)] = m[k];
}

extern "C" void kernel_launch(void* const* d_in, const int* in_sizes, int n_in,
                              void* d_out, int out_size, void* d_ws, size_t ws_size,
                              hipStream_t stream) {
    const float* feats = (const float*)d_in[0];
    const float* rois  = (const float*)d_in[1];
    float* out = (float*)d_out;

    const int Cc = 128, Hc = 64, Wc = 512;
    int nroi = in_sizes[1] / 5;
    int blocks = nroi * (Cc / CPT);

    ocr_roi_pool_kernel<<<blocks, 256, 0, stream>>>(feats, rois, out, Cc, Hc, Wc);
}